// Round 2
// baseline (14.819 us; speedup 1.0000x reference)
//
#include <hip/hip_runtime.h>
#include <math.h>

#define NPAIRS 7

__device__ __forceinline__ float2 cmul(float2 a, float2 b) {
    // a*b
    return make_float2(fmaf(a.x, b.x, -a.y * b.y), fmaf(a.x, b.y, a.y * b.x));
}
__device__ __forceinline__ float2 cmulc(float2 a, float2 b) {
    // a*conj(b)
    return make_float2(fmaf(a.x, b.x, a.y * b.y), fmaf(a.y, b.x, -a.x * b.y));
}
__device__ __forceinline__ float2 cadd(float2 a, float2 b) {
    return make_float2(a.x + b.x, a.y + b.y);
}

// alpha(i,k)[e]: complex coefficient of u[e] in A[i][k], where
// A = [[a0, ar+i*ai],[ar-i*ai, 1-a0]] and u = (1, a0, ar, ai).
__device__ __forceinline__ float2 alphav(int i, int k, int e) {
    if (i == 0 && k == 0) return make_float2(e == 1 ? 1.f : 0.f, 0.f);
    if (i == 0 && k == 1) return make_float2(e == 2 ? 1.f : 0.f, e == 3 ? 1.f : 0.f);
    if (i == 1 && k == 0) return make_float2(e == 2 ? 1.f : 0.f, e == 3 ? -1.f : 0.f);
    return make_float2(e == 0 ? 1.f : (e == 1 ? -1.f : 0.f), 0.f);
}

// -------- setup: compute 7 x 48 bilinear coefficients into cw --------------
// cw[p*48 + m*16 + e*4 + f], m=0: C_d0, m=1: C_or, m=2: C_oi
__global__ void __launch_bounds__(512)
qcnn_setup(const float* __restrict__ w, float* __restrict__ cw)
{
    __shared__ float2 Msh[NPAIRS][16];
    __shared__ float2 Ksh[NPAIRS][2][16];  // [pair][0=K0,1=Ko][r*4+s]

    const int tid = threadIdx.x;
    if (tid < NPAIRS) {
        const int k = tid;
        const float w0 = w[2 * k];
        const float w1 = w[2 * k + 1];
        float zr, zi, c1, s1;
        sincosf(0.5f * w0, &zi, &zr);   // z = e^{i w0/2}
        sincosf(0.5f * w1, &s1, &c1);
        const float cy = 0.92387953251128674f;  // cos(pi/8)
        const float sy = 0.38268343236508978f;  // sin(pi/8)

#pragma unroll
        for (int i = 0; i < 16; ++i) Msh[k][i] = make_float2(0.f, 0.f);

        // Composite M = CRY(pi/4; c=b,t=a) * CRX(w1; c=a,t=b) * CRZ(w0; c=a,t=b),
        // basis index = 2a+b. (verified correct in round-1 kernel)
        Msh[k][4 * 0 + 0] = make_float2(1.f, 0.f);
        Msh[k][4 * 1 + 1] = make_float2(cy, 0.f);
        Msh[k][4 * 1 + 2] = make_float2(sy * s1 * zi, sy * s1 * zr);
        Msh[k][4 * 1 + 3] = make_float2(-sy * c1 * zr, -sy * c1 * zi);
        Msh[k][4 * 2 + 2] = make_float2(c1 * zr, -c1 * zi);
        Msh[k][4 * 2 + 3] = make_float2(s1 * zi, -s1 * zr);
        Msh[k][4 * 3 + 1] = make_float2(sy, 0.f);
        Msh[k][4 * 3 + 2] = make_float2(-cy * s1 * zi, -cy * s1 * zr);
        Msh[k][4 * 3 + 3] = make_float2(cy * c1 * zr, cy * c1 * zi);
    }
    __syncthreads();

    // K0[r][s] = M[0][r]conj(M[0][s]) + M[1][r]conj(M[1][s])   (for d0')
    // Ko[r][s] = M[0][r]conj(M[2][s]) + M[1][r]conj(M[3][s])   (for o')
    if (tid < NPAIRS * 32) {
        const int p = tid >> 5;
        const int which = (tid >> 4) & 1;
        const int e = tid & 15;
        const int r = e >> 2, s = e & 3;
        float2 res;
        if (which == 0)
            res = cadd(cmulc(Msh[p][0 * 4 + r], Msh[p][0 * 4 + s]),
                       cmulc(Msh[p][1 * 4 + r], Msh[p][1 * 4 + s]));
        else
            res = cadd(cmulc(Msh[p][0 * 4 + r], Msh[p][2 * 4 + s]),
                       cmulc(Msh[p][1 * 4 + r], Msh[p][3 * 4 + s]));
        Ksh[p][which][e] = res;
    }
    __syncthreads();

    // C[e][f] = sum_{r,s} K[r,s] * alpha(i(r),k(s))[e] * alpha(m(r),l(s))[f]
    if (tid < NPAIRS * 48) {
        const int p = tid / 48;
        const int rem = tid % 48;
        const int outm = rem >> 4;          // 0:d0(Re,K0) 1:or(Re,Ko) 2:oi(Im,Ko)
        const int ef = rem & 15;
        const int e = ef >> 2, f = ef & 3;
        const float2* K = Ksh[p][outm == 0 ? 0 : 1];
        float2 acc = make_float2(0.f, 0.f);
        for (int r = 0; r < 4; ++r)
            for (int s = 0; s < 4; ++s) {
                const int i = r >> 1, m = r & 1, k = s >> 1, l = s & 1;
                const float2 a = alphav(i, k, e);
                const float2 b = alphav(m, l, f);
                acc = cadd(acc, cmul(cmul(K[r * 4 + s], a), b));
            }
        cw[tid] = (outm == 2) ? acc.y : acc.x;
    }
}

// -------- main ---------------------------------------------------------------
struct H3 { float d0, re, im; };  // rho = [[d0, re+i*im],[re-i*im, 1-d0]]

__device__ __forceinline__ void outer16(const H3 A, const H3 B, float wv[16]) {
    const float u1 = A.d0, u2 = A.re, u3 = A.im;
    const float v1 = B.d0, v2 = B.re, v3 = B.im;
    wv[0] = 1.f;      wv[1] = v1;       wv[2] = v2;       wv[3] = v3;
    wv[4] = u1;       wv[5] = u1 * v1;  wv[6] = u1 * v2;  wv[7] = u1 * v3;
    wv[8] = u2;       wv[9] = u2 * v1;  wv[10] = u2 * v2; wv[11] = u2 * v3;
    wv[12] = u3;      wv[13] = u3 * v1; wv[14] = u3 * v2; wv[15] = u3 * v3;
}

__device__ __forceinline__ H3 chan3(const H3 A, const H3 B, const float* __restrict__ c) {
    float wv[16];
    outer16(A, B, wv);
    float d = 0.f, re = 0.f, im = 0.f;
#pragma unroll
    for (int t = 0; t < 16; ++t) {
        d  = fmaf(c[t],      wv[t], d);
        re = fmaf(c[16 + t], wv[t], re);
        im = fmaf(c[32 + t], wv[t], im);
    }
    H3 R; R.d0 = d; R.re = re; R.im = im;
    return R;
}

__global__ void __launch_bounds__(256)
qcnn_main(const float* __restrict__ x, const float* __restrict__ cw,
          float* __restrict__ out, int batch)
{
    const int idx = blockIdx.x * 256 + threadIdx.x;
    if (idx >= batch) return;

    const float4 xa = reinterpret_cast<const float4*>(x)[2 * idx];
    const float4 xb = reinterpret_cast<const float4*>(x)[2 * idx + 1];
    const float xv[8] = {xa.x, xa.y, xa.z, xa.w, xb.x, xb.y, xb.z, xb.w};

    H3 r[8];
#pragma unroll
    for (int q = 0; q < 8; ++q) {
        float s, c;
        sincosf(xv[q], &s, &c);
        r[q].d0 = 0.5f * (1.f + c);
        r[q].re = 0.f;                 // leaf off-diagonal is purely imaginary
        r[q].im = 0.5f * s;
    }

    const H3 r01 = chan3(r[0], r[1], cw + 0 * 48);
    const H3 r23 = chan3(r[2], r[3], cw + 1 * 48);
    const H3 r45 = chan3(r[4], r[5], cw + 2 * 48);
    const H3 r67 = chan3(r[6], r[7], cw + 3 * 48);
    const H3 rA  = chan3(r01, r23, cw + 4 * 48);
    const H3 rB  = chan3(r45, r67, cw + 5 * 48);

    // final pair: only d0 needed; <Z0> = 2*d0' - 1
    float wv[16];
    outer16(rA, rB, wv);
    float d = 0.f;
#pragma unroll
    for (int t = 0; t < 16; ++t) d = fmaf(cw[6 * 48 + t], wv[t], d);

    out[idx] = 2.f * d - 1.f;
}

extern "C" void kernel_launch(void* const* d_in, const int* in_sizes, int n_in,
                              void* d_out, int out_size, void* d_ws, size_t ws_size,
                              hipStream_t stream) {
    const float* x = (const float*)d_in[0];
    const float* w = (const float*)d_in[1];
    float* out = (float*)d_out;
    float* cw = (float*)d_ws;            // 336 floats of channel coefficients
    const int batch = in_sizes[0] / 8;

    qcnn_setup<<<1, 512, 0, stream>>>(w, cw);
    qcnn_main<<<(batch + 255) / 256, 256, 0, stream>>>(x, cw, out, batch);
}

// Round 3
// 9.688 us; speedup vs baseline: 1.5296x; 1.5296x over previous
//
#include <hip/hip_runtime.h>
#include <math.h>

__device__ __forceinline__ float2 cmul(float2 a, float2 b) {
    // a*b
    return make_float2(fmaf(a.x, b.x, -a.y * b.y), fmaf(a.x, b.y, a.y * b.x));
}
__device__ __forceinline__ float2 cmulc(float2 a, float2 b) {
    // a*conj(b)
    return make_float2(fmaf(a.x, b.x, a.y * b.y), fmaf(a.y, b.x, -a.x * b.y));
}
__device__ __forceinline__ float2 cadd(float2 a, float2 b) {
    return make_float2(a.x + b.x, a.y + b.y);
}
__device__ __forceinline__ float2 cscale(float s, float2 a) {
    return make_float2(s * a.x, s * a.y);
}
__device__ __forceinline__ float2 conjf2(float2 a) { return make_float2(a.x, -a.y); }

// rho = [[d0, o],[conj(o), 1-d0]]
struct H3 { float d0; float2 o; };

// Per-pair channel coefficients, derived from the composite 4x4 gate
// M = CRY(pi/4; c=b,t=a) * CRX(w1) * CRZ(w0)  (basis 2a+b; verified round 1).
// M row structure: row0=(1,0,0,0); row1=(0,cy,m12,m13); row2=(0,0,m22,m23); row3=(0,sy,m32,m33).
// K1[r,s] = M[1,r]conj(M[1,s]) (Hermitian, r,s in {1,2,3}) -> d0'
// Ko[r,s] = M[1,r]conj(M[3,s])                             -> o'
struct Chan {
    float k11, k22, k33;            // real diagonal of K1
    float2 k12, k13, k23;           // upper triangle of K1
    float2 c22, c23;                // conj(m22), conj(m23)
    float ko11;                     // cy*sy (real)
    float2 ko12, ko13, ko21, ko22, ko23, ko31, ko32, ko33;
};

__device__ __forceinline__ Chan mkchan(float w0, float w1) {
    const float cy = 0.92387953251128674f;  // cos(pi/8)
    const float sy = 0.38268343236508978f;  // sin(pi/8)
    float zr, zi, c1, s1;
    __sincosf(0.5f * w0, &zi, &zr);   // z = e^{i w0/2}
    __sincosf(0.5f * w1, &s1, &c1);
    const float2 m12 = make_float2( sy * s1 * zi,  sy * s1 * zr);
    const float2 m13 = make_float2(-sy * c1 * zr, -sy * c1 * zi);
    const float2 m22 = make_float2( c1 * zr,      -c1 * zi);
    const float2 m23 = make_float2( s1 * zi,      -s1 * zr);
    const float2 m32 = make_float2(-cy * s1 * zi, -cy * s1 * zr);
    const float2 m33 = make_float2( cy * c1 * zr,  cy * c1 * zi);
    Chan C;
    C.k11 = cy * cy;
    C.k12 = cscale(cy, conjf2(m12));
    C.k13 = cscale(cy, conjf2(m13));
    C.k22 = fmaf(m12.x, m12.x, m12.y * m12.y);
    C.k23 = cmulc(m12, m13);
    C.k33 = fmaf(m13.x, m13.x, m13.y * m13.y);
    C.c22 = conjf2(m22);
    C.c23 = conjf2(m23);
    C.ko11 = cy * sy;
    C.ko12 = cscale(cy, conjf2(m32));
    C.ko13 = cscale(cy, conjf2(m33));
    C.ko21 = cscale(sy, m12);
    C.ko22 = cmulc(m12, m32);
    C.ko23 = cmulc(m12, m33);
    C.ko31 = cscale(sy, m13);
    C.ko32 = cmulc(m13, m32);
    C.ko33 = cmulc(m13, m33);
    return C;
}

// rho entries of A(x)B needed by the channel (basis r=2i+m over {a,b}):
// rho11=a0(1-b0) rho22=(1-a0)b0 rho33=(1-a0)(1-b0) [real]
// rho12=oA*conj(oB) rho13=oA(1-b0) rho23=(1-a0)oB rho02=oA*b0 rho03=oA*oB
__device__ __forceinline__ float chanD(const H3 A, const H3 B, const Chan& C) {
    const float a0 = A.d0, b0 = B.d0;
    const float p = a0 * b0;
    const float r11 = a0 - p, r22 = b0 - p, r33 = 1.f - a0 - b0 + p;
    const float2 rho12 = cmulc(A.o, B.o);
    const float2 rho13 = cscale(1.f - b0, A.o);
    const float2 rho23 = cscale(1.f - a0, B.o);
    float t = C.k12.x * rho12.x - C.k12.y * rho12.y
            + C.k13.x * rho13.x - C.k13.y * rho13.y
            + C.k23.x * rho23.x - C.k23.y * rho23.y;
    float d = p;
    d = fmaf(C.k11, r11, d);
    d = fmaf(C.k22, r22, d);
    d = fmaf(C.k33, r33, d);
    return fmaf(2.f, t, d);
}

__device__ __forceinline__ H3 chanK(const H3 A, const H3 B, const Chan& C) {
    const float a0 = A.d0, b0 = B.d0;
    const float p = a0 * b0;
    const float r11 = a0 - p, r22 = b0 - p, r33 = 1.f - a0 - b0 + p;
    const float2 rho12 = cmulc(A.o, B.o);
    const float2 rho13 = cscale(1.f - b0, A.o);
    const float2 rho23 = cscale(1.f - a0, B.o);
    const float2 rho02 = cscale(b0, A.o);
    const float2 rho03 = cmul(A.o, B.o);

    H3 R;
    {
        float t = C.k12.x * rho12.x - C.k12.y * rho12.y
                + C.k13.x * rho13.x - C.k13.y * rho13.y
                + C.k23.x * rho23.x - C.k23.y * rho23.y;
        float d = p;
        d = fmaf(C.k11, r11, d);
        d = fmaf(C.k22, r22, d);
        d = fmaf(C.k33, r33, d);
        R.d0 = fmaf(2.f, t, d);
    }
    // o' = rho02*conj(m22) + rho03*conj(m23) + sum Ko[r,s]*rho[r,s]
    float2 o = cmul(rho02, C.c22);
    o = cadd(o, cmul(rho03, C.c23));
    o.x = fmaf(C.ko11, r11, o.x);
    o = cadd(o, cmul(C.ko12, rho12));
    o = cadd(o, cmul(C.ko13, rho13));
    o = cadd(o, cmulc(C.ko21, rho12));   // Ko21 * conj(rho12)
    o = cadd(o, cscale(r22, C.ko22));
    o = cadd(o, cmul(C.ko23, rho23));
    o = cadd(o, cmulc(C.ko31, rho13));   // Ko31 * conj(rho13)
    o = cadd(o, cmulc(C.ko32, rho23));   // Ko32 * conj(rho23)
    o = cadd(o, cscale(r33, C.ko33));
    R.o = o;
    return R;
}

__global__ void __launch_bounds__(256, 1)
qcnn_fused(const float* __restrict__ x, const float* __restrict__ w,
           float* __restrict__ out, int batch)
{
    const int idx = blockIdx.x * 256 + threadIdx.x;
    if (idx >= batch) return;

    const float4 xa = reinterpret_cast<const float4*>(x)[2 * idx];
    const float4 xb = reinterpret_cast<const float4*>(x)[2 * idx + 1];
    const float xv[8] = {xa.x, xa.y, xa.z, xa.w, xb.x, xb.y, xb.z, xb.w};

    H3 r[8];
#pragma unroll
    for (int q = 0; q < 8; ++q) {
        float s, c;
        __sincosf(xv[q], &s, &c);
        r[q].d0 = 0.5f * (1.f + c);
        r[q].o  = make_float2(0.f, 0.5f * s);   // i*sin(x)/2
    }

    // w is wave-uniform: these become scalar loads; coefficient build is
    // ~60 VALU + 2 sincos per pair, built just-in-time to limit live range.
    const Chan C0 = mkchan(w[0],  w[1]);
    const H3 r01 = chanK(r[0], r[1], C0);
    const Chan C1 = mkchan(w[2],  w[3]);
    const H3 r23 = chanK(r[2], r[3], C1);
    const Chan C2 = mkchan(w[4],  w[5]);
    const H3 r45 = chanK(r[4], r[5], C2);
    const Chan C3 = mkchan(w[6],  w[7]);
    const H3 r67 = chanK(r[6], r[7], C3);
    const Chan C4 = mkchan(w[8],  w[9]);
    const H3 rA  = chanK(r01, r23, C4);
    const Chan C5 = mkchan(w[10], w[11]);
    const H3 rB  = chanK(r45, r67, C5);
    const Chan C6 = mkchan(w[12], w[13]);
    const float d = chanD(rA, rB, C6);   // only d0 needed; Ko parts of C6 are DCE'd

    out[idx] = 2.f * d - 1.f;            // <Z0> = 2*d0 - 1
}

extern "C" void kernel_launch(void* const* d_in, const int* in_sizes, int n_in,
                              void* d_out, int out_size, void* d_ws, size_t ws_size,
                              hipStream_t stream) {
    const float* x = (const float*)d_in[0];
    const float* w = (const float*)d_in[1];
    float* out = (float*)d_out;
    const int batch = in_sizes[0] / 8;
    qcnn_fused<<<(batch + 255) / 256, 256, 0, stream>>>(x, w, out, batch);
}

// Round 4
// 9.655 us; speedup vs baseline: 1.5348x; 1.0034x over previous
//
#include <hip/hip_runtime.h>
#include <math.h>

typedef float v2 __attribute__((ext_vector_type(2)));

__device__ __forceinline__ v2 mkv2(float x, float y) { v2 r; r.x = x; r.y = y; return r; }
__device__ __forceinline__ v2 swap2(v2 a) { return __builtin_shufflevector(a, a, 1, 0); }
__device__ __forceinline__ v2 splx(v2 a) { return __builtin_shufflevector(a, a, 0, 0); }
__device__ __forceinline__ v2 sply(v2 a) { return __builtin_shufflevector(a, a, 1, 1); }

// a*b = (ax*bx - ay*by, ax*by + ay*bx)  -- packed: 2 pk_mul + 1 pk_add(neg_lo)
__device__ __forceinline__ v2 cmul(v2 a, v2 b) {
    v2 s1 = splx(a) * b;            // (ax*bx, ax*by)
    v2 s2 = sply(a) * swap2(b);     // (ay*by, ay*bx)
    return s1 + mkv2(-s2.x, s2.y);
}
// a*conj(b) = (ax*bx + ay*by, ay*bx - ax*by)
__device__ __forceinline__ v2 cmulc(v2 a, v2 b) {
    v2 s1 = a * splx(b);            // (ax*bx, ay*bx)
    v2 s2 = swap2(a) * sply(b);     // (ay*by, ax*by)
    return s1 + mkv2(s2.x, -s2.y);
}
__device__ __forceinline__ v2 cscale(float s, v2 a) { return s * a; }
__device__ __forceinline__ v2 conjv(v2 a) { return mkv2(a.x, -a.y); }

// rho = [[d0, o],[conj(o), 1-d0]]
struct H3 { float d0; v2 o; };

// Per-pair channel coefficients, derived from the composite 4x4 gate
// M = CRY(pi/4; c=b,t=a) * CRX(w1) * CRZ(w0)  (basis 2a+b; verified round 1).
// Row structure: row0=(1,0,0,0); row1=(0,cy,m12,m13); row2=(0,0,m22,m23); row3=(0,sy,m32,m33).
struct Chan {
    float k11, k22, k33;            // real diagonal of K1 (K1[r,s]=M[1,r]conj(M[1,s]))
    v2 k12, k13, k23;               // upper triangle of K1
    v2 c22, c23;                    // conj(m22), conj(m23)
    float ko11;                     // cy*sy (real)   (Ko[r,s]=M[1,r]conj(M[3,s]))
    v2 ko12, ko13, ko21, ko22, ko23, ko31, ko32, ko33;
};

__device__ __forceinline__ Chan mkchan(float w0, float w1) {
    const float cy = 0.92387953251128674f;  // cos(pi/8)
    const float sy = 0.38268343236508978f;  // sin(pi/8)
    float zr, zi, c1, s1;
    __sincosf(0.5f * w0, &zi, &zr);   // z = e^{i w0/2}
    __sincosf(0.5f * w1, &s1, &c1);
    const v2 m12 = mkv2( sy * s1 * zi,  sy * s1 * zr);
    const v2 m13 = mkv2(-sy * c1 * zr, -sy * c1 * zi);
    const v2 m22 = mkv2( c1 * zr,      -c1 * zi);
    const v2 m23 = mkv2( s1 * zi,      -s1 * zr);
    const v2 m32 = mkv2(-cy * s1 * zi, -cy * s1 * zr);
    const v2 m33 = mkv2( cy * c1 * zr,  cy * c1 * zi);
    Chan C;
    C.k11 = cy * cy;
    C.k12 = cscale(cy, conjv(m12));
    C.k13 = cscale(cy, conjv(m13));
    C.k22 = fmaf(m12.x, m12.x, m12.y * m12.y);
    C.k23 = cmulc(m12, m13);
    C.k33 = fmaf(m13.x, m13.x, m13.y * m13.y);
    C.c22 = conjv(m22);
    C.c23 = conjv(m23);
    C.ko11 = cy * sy;
    C.ko12 = cscale(cy, conjv(m32));
    C.ko13 = cscale(cy, conjv(m33));
    C.ko21 = cscale(sy, m12);
    C.ko22 = cmulc(m12, m32);
    C.ko23 = cmulc(m12, m33);
    C.ko31 = cscale(sy, m13);
    C.ko32 = cmulc(m13, m32);
    C.ko33 = cmulc(m13, m33);
    return C;
}

// rho entries of A(x)B needed (basis r=2i+m over {a,b}):
// rho11=a0(1-b0) rho22=(1-a0)b0 rho33=(1-a0)(1-b0) [real]
// rho12=oA*conj(oB) rho13=oA(1-b0) rho23=(1-a0)oB rho02=oA*b0 rho03=oA*oB
__device__ __forceinline__ float chanD(const H3 A, const H3 B, const Chan& C) {
    const float a0 = A.d0, b0 = B.d0;
    const float p = a0 * b0;
    const float r11 = a0 - p, r22 = b0 - p, r33 = 1.f - a0 - b0 + p;
    const v2 rho12 = cmulc(A.o, B.o);
    const v2 rho13 = cscale(1.f - b0, A.o);
    const v2 rho23 = cscale(1.f - a0, B.o);
    // t = Re(k12*rho12) + Re(k13*rho13) + Re(k23*rho23) via packed dot halves
    const v2 tv = C.k12 * mkv2(rho12.x, -rho12.y)
                + C.k13 * mkv2(rho13.x, -rho13.y)
                + C.k23 * mkv2(rho23.x, -rho23.y);
    const float t = tv.x + tv.y;
    float d = p;
    d = fmaf(C.k11, r11, d);
    d = fmaf(C.k22, r22, d);
    d = fmaf(C.k33, r33, d);
    return fmaf(2.f, t, d);
}

__device__ __forceinline__ H3 chanK(const H3 A, const H3 B, const Chan& C) {
    const float a0 = A.d0, b0 = B.d0;
    const float p = a0 * b0;
    const float r11 = a0 - p, r22 = b0 - p, r33 = 1.f - a0 - b0 + p;
    const v2 rho12 = cmulc(A.o, B.o);
    const v2 rho13 = cscale(1.f - b0, A.o);
    const v2 rho23 = cscale(1.f - a0, B.o);
    const v2 rho02 = cscale(b0, A.o);
    const v2 rho03 = cmul(A.o, B.o);

    H3 R;
    {
        const v2 tv = C.k12 * mkv2(rho12.x, -rho12.y)
                    + C.k13 * mkv2(rho13.x, -rho13.y)
                    + C.k23 * mkv2(rho23.x, -rho23.y);
        const float t = tv.x + tv.y;
        float d = p;
        d = fmaf(C.k11, r11, d);
        d = fmaf(C.k22, r22, d);
        d = fmaf(C.k33, r33, d);
        R.d0 = fmaf(2.f, t, d);
    }
    // o' = rho02*conj(m22) + rho03*conj(m23) + sum Ko[r,s]*rho[r,s]
    v2 o = cmul(rho02, C.c22)
         + cmul(rho03, C.c23)
         + cmul(C.ko12, rho12)
         + cmul(C.ko13, rho13)
         + cmulc(C.ko21, rho12)    // Ko21 * conj(rho12)
         + cmul(C.ko23, rho23)
         + cmulc(C.ko31, rho13)    // Ko31 * conj(rho13)
         + cmulc(C.ko32, rho23)    // Ko32 * conj(rho23)
         + r22 * C.ko22
         + r33 * C.ko33;
    o.x = fmaf(C.ko11, r11, o.x);
    R.o = o;
    return R;
}

__global__ void __launch_bounds__(256, 1)
qcnn_fused(const float* __restrict__ x, const float* __restrict__ w,
           float* __restrict__ out, int batch)
{
    const int idx = blockIdx.x * 256 + threadIdx.x;
    if (idx >= batch) return;

    const float4 xa = reinterpret_cast<const float4*>(x)[2 * idx];
    const float4 xb = reinterpret_cast<const float4*>(x)[2 * idx + 1];
    const float xv[8] = {xa.x, xa.y, xa.z, xa.w, xb.x, xb.y, xb.z, xb.w};

    H3 r[8];
#pragma unroll
    for (int q = 0; q < 8; ++q) {
        float s, c;
        __sincosf(xv[q], &s, &c);
        r[q].d0 = 0.5f * (1.f + c);
        r[q].o  = mkv2(0.f, 0.5f * s);   // i*sin(x)/2
    }

    // w is wave-uniform: scalar loads; coefficient build ~60 VALU + 2 sincos
    // per pair, built just-in-time to limit live range.
    const Chan C0 = mkchan(w[0],  w[1]);
    const H3 r01 = chanK(r[0], r[1], C0);
    const Chan C1 = mkchan(w[2],  w[3]);
    const H3 r23 = chanK(r[2], r[3], C1);
    const Chan C2 = mkchan(w[4],  w[5]);
    const H3 r45 = chanK(r[4], r[5], C2);
    const Chan C3 = mkchan(w[6],  w[7]);
    const H3 r67 = chanK(r[6], r[7], C3);
    const Chan C4 = mkchan(w[8],  w[9]);
    const H3 rA  = chanK(r01, r23, C4);
    const Chan C5 = mkchan(w[10], w[11]);
    const H3 rB  = chanK(r45, r67, C5);
    const Chan C6 = mkchan(w[12], w[13]);
    const float d = chanD(rA, rB, C6);   // only d0 needed; rest of C6 DCE'd

    out[idx] = 2.f * d - 1.f;            // <Z0> = 2*d0 - 1
}

extern "C" void kernel_launch(void* const* d_in, const int* in_sizes, int n_in,
                              void* d_out, int out_size, void* d_ws, size_t ws_size,
                              hipStream_t stream) {
    const float* x = (const float*)d_in[0];
    const float* w = (const float*)d_in[1];
    float* out = (float*)d_out;
    const int batch = in_sizes[0] / 8;
    qcnn_fused<<<(batch + 255) / 256, 256, 0, stream>>>(x, w, out, batch);
}